// Round 7
// baseline (237.430 us; speedup 1.0000x reference)
//
#include <hip/hip_runtime.h>

#define NQ 4096
#define NM 8192
#define DK 128
#define DV 512
#define BATCH 2
#define NT (NM / 64)        // 128 m-tiles per batch
#define KTS 8192            // shorts per K tile: 64 rows x 128 dk (tile-linear swizzled)
#define VTILE 16384         // shorts per (b, mtile, dvh) V tile: 256 dv x 64 m

typedef __attribute__((ext_vector_type(8))) short short8;
typedef __attribute__((ext_vector_type(4))) float f32x4;
typedef unsigned short ushort_t;

#define MF(A_, B_, C_) __builtin_amdgcn_mfma_f32_16x16x32_bf16(A_, B_, C_, 0, 0, 0)

static __device__ __forceinline__ unsigned short f2bf(float x) {
    union { float f; unsigned int u; } c; c.f = x;
    unsigned int u = c.u;
    return (unsigned short)((u + 0x7FFFu + ((u >> 16) & 1u)) >> 16);
}
static __device__ __forceinline__ float bf2f(unsigned short h) {
    union { unsigned int u; float f; } c; c.u = ((unsigned int)h) << 16;
    return c.f;
}

// swizzled V-image address for (compacted pos, dv) within batch image
static __device__ __forceinline__ size_t vaddr(int b, int pos, int dv) {
    const int mt = pos >> 6, m64 = pos & 63;
    const int dvh = dv >> 8, rr = dv & 255;
    return (((size_t)(b * NT + mt) * 2 + dvh) * VTILE)
         + (rr >> 6) * 4096 + ((rr >> 4) & 3) * 1024
         + (m64 >> 5) * 512
         + ((((m64 >> 4) & 1) * 2 + ((m64 >> 3) & 1)) * 128)
         + (rr & 15) * 8 + (m64 & 7);
}

// K-tile register fragment load (1KB contiguous per wave per b128)
#define LOADK(AH, AL, itn_) do {                                              \
    const size_t ktb_ = kbase + (size_t)(itn_) * KTS;                         \
    _Pragma("unroll")                                                         \
    for (int ks_ = 0; ks_ < 4; ++ks_) {                                       \
        AH[ks_] = *(const short8*)(kh0 + ktb_ + ks_ * 512);                   \
        AL[ks_] = *(const short8*)(kl0 + ktb_ + ks_ * 512);                   \
    }                                                                         \
} while (0)

// ---------------------------------------------------------------------------
// scan: per-batch compaction of mmask (shfl wave scans). Unchanged.
// ---------------------------------------------------------------------------
__global__ __launch_bounds__(1024) void scan_kernel(
    const int* __restrict__ qmask, const int* __restrict__ mmask,
    int* __restrict__ cidx, int* __restrict__ cpos,
    int* __restrict__ cnts, int* __restrict__ qflags) {
    const int b = blockIdx.x;
    const int t = threadIdx.x;
    const int lane = t & 63;
    const int w = t >> 6;
    __shared__ int wsum[16];
    __shared__ int qsh;

    const int* mp = mmask + b * NM;
    const int base = t * 8;
    int val[8];
#pragma unroll
    for (int i = 0; i < 8; ++i) val[i] = (mp[base + i] != 0);
    int c0 = 0;
#pragma unroll
    for (int i = 0; i < 8; ++i) c0 += val[i];

    int c = c0;
#pragma unroll
    for (int off = 1; off < 64; off <<= 1) {
        int n = __shfl_up(c, off, 64);
        if (lane >= off) c += n;
    }
    if (lane == 63) wsum[w] = c;
    if (t == 0) qsh = 0;
    __syncthreads();
    if (t == 0) {
        int s = 0;
#pragma unroll
        for (int i = 0; i < 16; ++i) { s += wsum[i]; wsum[i] = s; }
    }
    __syncthreads();
    const int wbase = (w == 0) ? 0 : wsum[w - 1];
    int run = wbase + (c - c0);
#pragma unroll
    for (int i = 0; i < 8; ++i) {
        int m = base + i;
        cpos[b * NM + m] = run;
        if (val[i]) { cidx[b * NM + run] = m; ++run; }
    }

    int qa = 0;
    for (int i = t; i < NQ; i += 1024) qa |= (qmask[b * NQ + i] != 0);
    if (qa) atomicOr(&qsh, 1);
    __syncthreads();
    if (t == 0) { cnts[b] = wsum[15]; qflags[b] = qsh; }
}

// ---------------------------------------------------------------------------
// prep Q: transpose [B][DK][NQ] fp32 -> [B][q][DK] bf16 hi/lo (dense rows)
// ---------------------------------------------------------------------------
__global__ __launch_bounds__(256) void prep_q_kernel(
    const float* __restrict__ src, ushort_t* __restrict__ hi,
    ushort_t* __restrict__ lo) {
    const int b = blockIdx.z;
    const int d0 = blockIdx.y * 32;
    const int n0 = blockIdx.x * 32;
    __shared__ float t32[32][33];
    for (int l = threadIdx.x; l < 1024; l += 256) {
        int r = l >> 5, c = l & 31;
        t32[r][c] = src[((size_t)b * DK + d0 + r) * NQ + n0 + c];
    }
    __syncthreads();
    for (int l = threadIdx.x; l < 1024; l += 256) {
        int r = l >> 5, c = l & 31;
        float f = t32[c][r];
        unsigned short h = f2bf(f);
        unsigned short lw = f2bf(f - bf2f(h));
        size_t off = ((size_t)b * NQ + n0 + r) * DK + d0 + c;
        hi[off] = h;
        lo[off] = lw;
    }
}

// ---------------------------------------------------------------------------
// prep K: transpose + compacting gather -> tile-linear swizzled image.
// Per 64-row tile (16 KB): [w:4][ks:4][quad:4][col:16] x 8 shorts, so a wave's
// b128 fragment read (w,ks fixed; lane = quad*16+col) is one contiguous 1 KB.
// ---------------------------------------------------------------------------
__global__ __launch_bounds__(256) void prep_k_kernel(
    const float* __restrict__ src, const int* __restrict__ mmask,
    const int* __restrict__ cpos,
    ushort_t* __restrict__ hi, ushort_t* __restrict__ lo) {
    const int b = blockIdx.z;
    const int d0 = blockIdx.y * 32;
    const int n0 = blockIdx.x * 32;
    __shared__ float t32[32][33];
    for (int l = threadIdx.x; l < 1024; l += 256) {
        int r = l >> 5, c = l & 31;
        t32[r][c] = src[((size_t)b * DK + d0 + r) * NM + n0 + c];
    }
    __syncthreads();
    for (int l = threadIdx.x; l < 1024; l += 256) {
        int r = l >> 5, c = l & 31;
        int m = n0 + r;
        if (mmask[b * NM + m] != 0) {
            int pos = cpos[b * NM + m];
            float f = t32[c][r];
            unsigned short h = f2bf(f);
            unsigned short lw = f2bf(f - bf2f(h));
            int d = d0 + c;
            size_t off = ((size_t)(b * NT + (pos >> 6))) * KTS
                       + ((pos >> 4) & 3) * 2048 + (d >> 5) * 512
                       + ((d >> 3) & 3) * 128 + (pos & 15) * 8 + (d & 7);
            hi[off] = h;
            lo[off] = lw;
        }
    }
}

// ---------------------------------------------------------------------------
// prep V (dense-read compaction): read mval coalesced (float4 along m),
// predicated-write bf16 to the swizzled compacted V image. blockIdx.y==8
// branch zero-fills only the tail tile. grid (DV/8, 9, B), 256 thr.
// ---------------------------------------------------------------------------
__global__ __launch_bounds__(256) void prep_v_kernel(
    const float* __restrict__ src, const int* __restrict__ mmask,
    const int* __restrict__ cpos, const int* __restrict__ cnts,
    ushort_t* __restrict__ dst) {
    const int b = blockIdx.z;
    const int dv0 = blockIdx.x * 8;
    if (blockIdx.y == 8) {   // tail-tile zero fill: pos in [cnt, nit*64)
        const int cnt = cnts[b];
        const int pend = ((cnt + 63) >> 6) * 64;
        const int dv = dv0 + (threadIdx.x >> 5);
        for (int p = cnt + (threadIdx.x & 31); p < pend; p += 32)
            dst[vaddr(b, p, dv)] = 0;
        return;
    }
    const int m = blockIdx.y * 1024 + threadIdx.x * 4;
    const int4 mm = *(const int4*)(mmask + b * NM + m);
    const int4 cp = *(const int4*)(cpos + b * NM + m);
#pragma unroll
    for (int i = 0; i < 8; ++i) {
        const int dv = dv0 + i;
        const float4 v = *(const float4*)(src + ((size_t)b * DV + dv) * NM + m);
        if (mm.x) dst[vaddr(b, cp.x, dv)] = f2bf(v.x);
        if (mm.y) dst[vaddr(b, cp.y, dv)] = f2bf(v.y);
        if (mm.z) dst[vaddr(b, cp.z, dv)] = f2bf(v.z);
        if (mm.w) dst[vaddr(b, cp.w, dv)] = f2bf(v.w);
    }
}

// ---------------------------------------------------------------------------
// stats-lite: hi*hi-only max per (q-tile, m-quarter). pv merges 4 parts +8.
// grid 1024 = 128 qt x 4 parts x 2 b, 256 thr. (unchanged from r6)
// ---------------------------------------------------------------------------
__global__ __launch_bounds__(256, 4) void stats_kernel(
    const ushort_t* __restrict__ Qhi, const ushort_t* __restrict__ Khi,
    const int* __restrict__ cnts, float* __restrict__ mpart) {
    const int t = threadIdx.x;
    const int lane = t & 63;
    const int w = t >> 6;
    const int quad = lane >> 4;
    const int col = lane & 15;
    const int bid = blockIdx.x;
    const int part = bid & 3;
    const int b = (bid >> 2) & 1;
    const int qb = (bid >> 3) * 32;

    const int cnt = cnts[b];
    const int nit = (cnt + 63) >> 6;
    const int it0 = (nit * part) >> 2;
    const int it1 = (nit * (part + 1)) >> 2;

    __shared__ float red_m[4][32];

    short8 qfh[2][4];
    {
        const ushort_t* qhp = Qhi + ((size_t)b * NQ + qb) * DK;
#pragma unroll
        for (int qt = 0; qt < 2; ++qt)
#pragma unroll
            for (int ks = 0; ks < 4; ++ks)
                qfh[qt][ks] = *(const short8*)(qhp + (size_t)(qt * 16 + col) * DK + ks * 32 + quad * 8);
    }

    const f32x4 zero4 = {0.f, 0.f, 0.f, 0.f};
    float mloc[2] = {-3.0e38f, -3.0e38f};
    const ushort_t* kh0 = Khi + w * 2048 + lane * 8;
    const size_t kbase = (size_t)(b * NT) * KTS;

#define LOADKH(A_, itn_) do {                                                 \
    const size_t ktb_ = kbase + (size_t)(itn_) * KTS;                         \
    _Pragma("unroll")                                                         \
    for (int ks_ = 0; ks_ < 4; ++ks_)                                         \
        A_[ks_] = *(const short8*)(kh0 + ktb_ + ks_ * 512);                   \
} while (0)

#define STPH(CK, NK, it_, itn_) do {                                          \
    LOADKH(NK, itn_);                                                         \
    f32x4 aS0 = zero4, aS1 = zero4;                                           \
    _Pragma("unroll")                                                         \
    for (int ks = 0; ks < 4; ++ks) {                                          \
        aS0 = MF(CK[ks], qfh[0][ks], aS0);                                    \
        aS1 = MF(CK[ks], qfh[1][ks], aS1);                                    \
    }                                                                         \
    const int mrow_ = (it_) * 64 + w * 16 + quad * 4;                         \
    _Pragma("unroll")                                                         \
    for (int r = 0; r < 4; ++r) {                                             \
        if (mrow_ + r < cnt) {                                                \
            mloc[0] = fmaxf(mloc[0], aS0[r] * 40.0f);                         \
            mloc[1] = fmaxf(mloc[1], aS1[r] * 40.0f);                         \
        }                                                                     \
    }                                                                         \
} while (0)

    short8 kA[4], kB[4];
    int it = it0;
    if (it < it1) {
        LOADKH(kA, it);
        int itn;
        while (true) {
            itn = (it + 1 < it1) ? it + 1 : it;
            STPH(kA, kB, it, itn);
            if (++it >= it1) break;
            itn = (it + 1 < it1) ? it + 1 : it;
            STPH(kB, kA, it, itn);
            if (++it >= it1) break;
        }
    }
#undef STPH
#undef LOADKH

#pragma unroll
    for (int qt = 0; qt < 2; ++qt) {
        float m = mloc[qt];
        m = fmaxf(m, __shfl_xor(m, 16, 64));
        m = fmaxf(m, __shfl_xor(m, 32, 64));
        if (lane < 16) red_m[w][qt * 16 + col] = m;
    }
    __syncthreads();
    if (t < 32) {
        float M = -3.0e38f;
#pragma unroll
        for (int ww = 0; ww < 4; ++ww) M = fmaxf(M, red_m[ww][t]);
        mpart[((size_t)(b * 4 + part)) * NQ + qb + t] = M;
    }
}

// ---------------------------------------------------------------------------
// pv: q-tile 64 (halves K/V traffic: 3 GB -> 1.5 GB through L2), both Q limbs
// staged in LDS fragment layout (keeps VGPR < 2-wave cap), single-buffer K,
// P double-buffer, one lgkm-only barrier per phase (r6-verified). 2-way
// m-chunk: (chunk,dvh,b) = bid&7 -> each XCD's working set = 3 MB, L2-fit.
// Exact per-chunk l via all-ones MFMA (dvh==0, w==0). grid 512, 256 thr.
// ---------------------------------------------------------------------------
__global__ __launch_bounds__(256, 2) void pv_kernel(
    const ushort_t* __restrict__ Qhi, const ushort_t* __restrict__ Qlo,
    const ushort_t* __restrict__ Khi, const ushort_t* __restrict__ Klo,
    const ushort_t* __restrict__ Vimg, const int* __restrict__ cnts,
    const float* __restrict__ mpart, float* __restrict__ out0,
    float* __restrict__ out1, float* __restrict__ lsum) {
    const int t = threadIdx.x;
    const int lane = t & 63;
    const int w = t >> 6;
    const int quad = lane >> 4;
    const int col = lane & 15;
    const int bid = blockIdx.x;
    const int chunk = bid & 1;
    const int dvh = (bid >> 1) & 1;
    const int b = (bid >> 2) & 1;
    const int qb = (bid >> 3) * 64;

    const int cnt = cnts[b];
    const int nit = (cnt + 63) >> 6;
    const int nh = (nit + 1) >> 1;
    const int it0 = chunk ? nh : 0;
    const int it1 = chunk ? nit : nh;

    __shared__ __align__(16) ushort_t Q_s[2][4][4][512];     // 32 KB: [limb][qt][ks][lane*8]
    __shared__ __align__(16) ushort_t P_s[2][64][68];        // 17.4 KB

    // inline finalize: merge 4 stats parts + margin for dropped lo-products
    float gm[4];
#pragma unroll
    for (int qt = 0; qt < 4; ++qt) {
        float M = -3.0e38f;
#pragma unroll
        for (int c = 0; c < 4; ++c)
            M = fmaxf(M, mpart[((size_t)(b * 4 + c)) * NQ + qb + qt * 16 + col]);
        gm[qt] = M + 8.0f;
    }

    {   // stage Q hi/lo into LDS fragment layout (row r = t>>2, dk chunk t&3)
        const int r = t >> 2, ks4 = t & 3;
        const int qt_ = r >> 4, col_ = r & 15;
        const ushort_t* qhp = Qhi + ((size_t)b * NQ + qb + r) * DK + ks4 * 32;
        const ushort_t* qlp = Qlo + ((size_t)b * NQ + qb + r) * DK + ks4 * 32;
#pragma unroll
        for (int qd = 0; qd < 4; ++qd) {
            *(short8*)&Q_s[0][qt_][ks4][qd * 128 + col_ * 8] = *(const short8*)(qhp + qd * 8);
            *(short8*)&Q_s[1][qt_][ks4][qd * 128 + col_ * 8] = *(const short8*)(qlp + qd * 8);
        }
    }
    __syncthreads();

    const ushort_t* kh0 = Khi + w * 2048 + lane * 8;
    const ushort_t* kl0 = Klo + w * 2048 + lane * 8;
    const size_t kbase = (size_t)(b * NT) * KTS;
    const ushort_t* vl0 = Vimg + ((size_t)(b * NT) * 2 + dvh) * VTILE
                        + w * 4096 + lane * 8;

    const f32x4 zero4 = {0.f, 0.f, 0.f, 0.f};
    const short8 vones = {(short)0x3F80, (short)0x3F80, (short)0x3F80,
                          (short)0x3F80, (short)0x3F80, (short)0x3F80,
                          (short)0x3F80, (short)0x3F80};
    const bool doL = (dvh == 0) && (w == 0);
    f32x4 accO[4][4];   // [vt][qt]
#pragma unroll
    for (int vt = 0; vt < 4; ++vt)
#pragma unroll
        for (int qt = 0; qt < 4; ++qt) accO[vt][qt] = zero4;
    f32x4 accL[4];
#pragma unroll
    for (int qt = 0; qt < 4; ++qt) accL[qt] = zero4;

    for (int it = it0; it < it1; ++it) {
        const int pb = (it - it0) & 1;
        // ---- K frags (single-buffered; consumed by QK below) ----
        short8 kh[4], kl[4];
        LOADK(kh, kl, it);
        // ---- QK: Q limbs streamed from LDS (3 limb-products, lo*lo dropped) ----
        f32x4 aS[4];
#pragma unroll
        for (int qt = 0; qt < 4; ++qt) aS[qt] = zero4;
#pragma unroll
        for (int qt = 0; qt < 4; ++qt) {
#pragma unroll
            for (int ks = 0; ks < 4; ++ks) {
                const short8 qh = *(const short8*)&Q_s[0][qt][ks][lane * 8];
                const short8 ql = *(const short8*)&Q_s[1][qt][ks][lane * 8];
                aS[qt] = MF(kh[ks], qh, aS[qt]);
                aS[qt] = MF(kh[ks], ql, aS[qt]);
                aS[qt] = MF(kl[ks], qh, aS[qt]);
            }
        }
        // ---- V frags (issued here; stay in flight across the barrier) ----
        const ushort_t* vp = vl0 + (size_t)it * (2 * VTILE);
        short8 vf[4][2];
#pragma unroll
        for (int vt = 0; vt < 4; ++vt) {
            vf[vt][0] = *(const short8*)(vp + vt * 1024);
            vf[vt][1] = *(const short8*)(vp + vt * 1024 + 512);
        }
        // ---- P = exp(s - gmax) -> LDS (double-buffered) ----
        const int mrow = it * 64 + w * 16 + quad * 4;
#pragma unroll
        for (int qt = 0; qt < 4; ++qt) {
            float p[4];
#pragma unroll
            for (int r = 0; r < 4; ++r)
                p[r] = (mrow + r < cnt) ? __expf(aS[qt][r] * 40.0f - gm[qt]) : 0.0f;
            ushort4 pk;
            pk.x = f2bf(p[0]); pk.y = f2bf(p[1]);
            pk.z = f2bf(p[2]); pk.w = f2bf(p[3]);
            *(ushort4*)&P_s[pb][qt * 16 + col][w * 16 + quad * 4] = pk;
        }
        asm volatile("s_waitcnt lgkmcnt(0)" ::: "memory");
        __builtin_amdgcn_s_barrier();
        __builtin_amdgcn_sched_barrier(0);
        // ---- PV ----
#pragma unroll
        for (int k2 = 0; k2 < 2; ++k2) {
            short8 pq[4];
#pragma unroll
            for (int qt = 0; qt < 4; ++qt)
                pq[qt] = *(const short8*)&P_s[pb][qt * 16 + col][k2 * 32 + quad * 8];
#pragma unroll
            for (int vt = 0; vt < 4; ++vt)
#pragma unroll
                for (int qt = 0; qt < 4; ++qt)
                    accO[vt][qt] = MF(vf[vt][k2], pq[qt], accO[vt][qt]);
            if (doL) {
#pragma unroll
                for (int qt = 0; qt < 4; ++qt)
                    accL[qt] = MF(vones, pq[qt], accL[qt]);
            }
        }
    }

    // ---- epilogue: raw partial sums (normalization+gating in combine) ----
    float* pbase = chunk ? out1 : out0;
#pragma unroll
    for (int qt = 0; qt < 4; ++qt) {
        const int q = qb + qt * 16 + col;
#pragma unroll
        for (int vt = 0; vt < 4; ++vt)
#pragma unroll
            for (int r = 0; r < 4; ++r) {
                int dv = dvh * 256 + w * 64 + vt * 16 + quad * 4 + r;
                pbase[((size_t)b * DV + dv) * NQ + q] = accO[vt][qt][r];
            }
    }
    // exact per-chunk softmax denominator (all rows of accL identical)
    if (doL && lane < 16) {
#pragma unroll
        for (int qt = 0; qt < 4; ++qt)
            lsum[((size_t)(b * 2 + chunk)) * NQ + qb + qt * 16 + col] = accL[qt][0];
    }
}

// ---------------------------------------------------------------------------
// combine: out = gated (p0 + p1) / (l0 + l1)   (p0 aliases out; elementwise)
// ---------------------------------------------------------------------------
__global__ __launch_bounds__(256) void combine_kernel(
    const float* p0, const float* __restrict__ p1,
    const float* __restrict__ lsum, const int* __restrict__ cnts,
    const int* __restrict__ qflags, const int* __restrict__ qmask,
    float* out) {
    const size_t i = ((size_t)blockIdx.x * 256 + threadIdx.x) * 4;
    const int b = (int)(i >> 21);          // DV*NQ = 2^21
    const int q = (int)(i & (NQ - 1));
    f32x4 a = *(const f32x4*)(p0 + i);
    f32x4 c = *(const f32x4*)(p1 + i);
    f32x4 l0 = *(const f32x4*)(lsum + (size_t)(b * 2) * NQ + q);
    f32x4 l1 = *(const f32x4*)(lsum + (size_t)(b * 2 + 1) * NQ + q);
    const int4 qm = *(const int4*)(qmask + b * NQ + q);
    const bool bv = (qflags[b] != 0) && (cnts[b] > 0);
    f32x4 r;
    float lv;
    lv = l0[0] + l1[0]; r[0] = (bv && qm.x && lv > 0.f) ? (a[0] + c[0]) / lv : 0.f;
    lv = l0[1] + l1[1]; r[1] = (bv && qm.y && lv > 0.f) ? (a[1] + c[1]) / lv : 0.f;
    lv = l0[2] + l1[2]; r[2] = (bv && qm.z && lv > 0.f) ? (a[2] + c[2]) / lv : 0.f;
    lv = l0[3] + l1[3]; r[3] = (bv && qm.w && lv > 0.f) ? (a[3] + c[3]) / lv : 0.f;
    *(f32x4*)(out + i) = r;
}

// ---------------------------------------------------------------------------
extern "C" void kernel_launch(void* const* d_in, const int* in_sizes, int n_in,
                              void* d_out, int out_size, void* d_ws, size_t ws_size,
                              hipStream_t stream) {
    const float* qkey  = (const float*)d_in[0];
    // d_in[1] (qval) unused by the reference
    const int*   qmask = (const int*)d_in[2];
    const float* mkey  = (const float*)d_in[3];
    const float* mval  = (const float*)d_in[4];
    const int*   mmask = (const int*)d_in[5];
    float* out = (float*)d_out;

    char* ws = (char*)d_ws;
    size_t off = 0;
    const size_t QS  = (size_t)BATCH * NQ * DK * 2;          // 2 MB each
    const size_t KS2 = (size_t)BATCH * NM * DK * 2;          // 4 MB each (swizzled)
    const size_t VS  = (size_t)BATCH * NT * 2 * VTILE * 2;   // 16 MB
    const size_t OS  = (size_t)BATCH * DV * NQ * 4;          // 16.8 MB
    ushort_t* Qhi = (ushort_t*)(ws + off); off += QS;
    ushort_t* Qlo = (ushort_t*)(ws + off); off += QS;
    ushort_t* Khi = (ushort_t*)(ws + off); off += KS2;
    ushort_t* Klo = (ushort_t*)(ws + off); off += KS2;
    ushort_t* Vc  = (ushort_t*)(ws + off); off += VS;
    float* part1  = (float*)(ws + off); off += OS;           // chunk-1 partial
    float* mpart  = (float*)(ws + off); off += (size_t)BATCH * 4 * NQ * 4;
    float* lsum   = (float*)(ws + off); off += (size_t)BATCH * 2 * NQ * 4;
    int* cidx     = (int*)(ws + off); off += (size_t)BATCH * NM * 4;
    int* cpos     = (int*)(ws + off); off += (size_t)BATCH * NM * 4;
    int* cnts     = (int*)(ws + off); off += 64;
    int* qflags   = (int*)(ws + off); off += 64;

    scan_kernel<<<BATCH, 1024, 0, stream>>>(qmask, mmask, cidx, cpos, cnts, qflags);

    dim3 gq(NQ / 32, DK / 32, BATCH);
    prep_q_kernel<<<gq, 256, 0, stream>>>(qkey, Qhi, Qlo);
    dim3 gk(NM / 32, DK / 32, BATCH);
    prep_k_kernel<<<gk, 256, 0, stream>>>(mkey, mmask, cpos, Khi, Klo);

    dim3 gv(DV / 8, 9, BATCH);
    prep_v_kernel<<<gv, 256, 0, stream>>>(mval, mmask, cpos, cnts, Vc);

    stats_kernel<<<(NQ / 32) * 8, 256, 0, stream>>>(Qhi, Khi, cnts, mpart);

    pv_kernel<<<(NQ / 64) * 8, 256, 0, stream>>>(
        Qhi, Qlo, Khi, Klo, Vc, cnts, mpart, out, part1, lsum);

    combine_kernel<<<(int)((size_t)BATCH * DV * NQ / 1024), 256, 0, stream>>>(
        out, part1, lsum, cnts, qflags, qmask, out);
}

// Round 8
// 233.927 us; speedup vs baseline: 1.0150x; 1.0150x over previous
//
#include <hip/hip_runtime.h>

#define NQ 4096
#define NM 8192
#define DK 128
#define DV 512
#define BATCH 2
#define NT (NM / 64)        // 128 m-tiles per batch
#define KTS 8192            // shorts per K tile: 64 rows x 128 dk (tile-linear swizzled)
#define VTILE 16384         // shorts per (b, mtile, dvh) V tile: 256 dv x 64 m

typedef __attribute__((ext_vector_type(8))) short short8;
typedef __attribute__((ext_vector_type(4))) float f32x4;
typedef unsigned short ushort_t;

#define MF(A_, B_, C_) __builtin_amdgcn_mfma_f32_16x16x32_bf16(A_, B_, C_, 0, 0, 0)

static __device__ __forceinline__ unsigned short f2bf(float x) {
    union { float f; unsigned int u; } c; c.f = x;
    unsigned int u = c.u;
    return (unsigned short)((u + 0x7FFFu + ((u >> 16) & 1u)) >> 16);
}
static __device__ __forceinline__ float bf2f(unsigned short h) {
    union { unsigned int u; float f; } c; c.u = ((unsigned int)h) << 16;
    return c.f;
}

// swizzled V-image address for (compacted pos, dv) within batch image
static __device__ __forceinline__ size_t vaddr(int b, int pos, int dv) {
    const int mt = pos >> 6, m64 = pos & 63;
    const int dvh = dv >> 8, rr = dv & 255;
    return (((size_t)(b * NT + mt) * 2 + dvh) * VTILE)
         + (rr >> 6) * 4096 + ((rr >> 4) & 3) * 1024
         + (m64 >> 5) * 512
         + ((((m64 >> 4) & 1) * 2 + ((m64 >> 3) & 1)) * 128)
         + (rr & 15) * 8 + (m64 & 7);
}

// K-tile register fragment load (1KB contiguous per wave per b128)
#define LOADK(AH, AL, itn_) do {                                              \
    const size_t ktb_ = kbase + (size_t)(itn_) * KTS;                         \
    _Pragma("unroll")                                                         \
    for (int ks_ = 0; ks_ < 4; ++ks_) {                                       \
        AH[ks_] = *(const short8*)(kh0 + ktb_ + ks_ * 512);                   \
        AL[ks_] = *(const short8*)(kl0 + ktb_ + ks_ * 512);                   \
    }                                                                         \
} while (0)

// ---------------------------------------------------------------------------
// scan: per-batch compaction of mmask (shfl wave scans). Unchanged.
// ---------------------------------------------------------------------------
__global__ __launch_bounds__(1024) void scan_kernel(
    const int* __restrict__ qmask, const int* __restrict__ mmask,
    int* __restrict__ cidx, int* __restrict__ cpos,
    int* __restrict__ cnts, int* __restrict__ qflags) {
    const int b = blockIdx.x;
    const int t = threadIdx.x;
    const int lane = t & 63;
    const int w = t >> 6;
    __shared__ int wsum[16];
    __shared__ int qsh;

    const int* mp = mmask + b * NM;
    const int base = t * 8;
    int val[8];
#pragma unroll
    for (int i = 0; i < 8; ++i) val[i] = (mp[base + i] != 0);
    int c0 = 0;
#pragma unroll
    for (int i = 0; i < 8; ++i) c0 += val[i];

    int c = c0;
#pragma unroll
    for (int off = 1; off < 64; off <<= 1) {
        int n = __shfl_up(c, off, 64);
        if (lane >= off) c += n;
    }
    if (lane == 63) wsum[w] = c;
    if (t == 0) qsh = 0;
    __syncthreads();
    if (t == 0) {
        int s = 0;
#pragma unroll
        for (int i = 0; i < 16; ++i) { s += wsum[i]; wsum[i] = s; }
    }
    __syncthreads();
    const int wbase = (w == 0) ? 0 : wsum[w - 1];
    int run = wbase + (c - c0);
#pragma unroll
    for (int i = 0; i < 8; ++i) {
        int m = base + i;
        cpos[b * NM + m] = run;
        if (val[i]) { cidx[b * NM + run] = m; ++run; }
    }

    int qa = 0;
    for (int i = t; i < NQ; i += 1024) qa |= (qmask[b * NQ + i] != 0);
    if (qa) atomicOr(&qsh, 1);
    __syncthreads();
    if (t == 0) { cnts[b] = wsum[15]; qflags[b] = qsh; }
}

// ---------------------------------------------------------------------------
// fused prep: one launch runs prep_q (blocks [0,1024)), prep_k ([1024,3072)),
// prep_v ([3072,4224)). Removes 2 launch gaps; segments overlap across CUs.
// ---------------------------------------------------------------------------
__global__ __launch_bounds__(256) void prep_all_kernel(
    const float* __restrict__ qkey, const float* __restrict__ mkey,
    const float* __restrict__ mval, const int* __restrict__ mmask,
    const int* __restrict__ cpos, const int* __restrict__ cnts,
    ushort_t* __restrict__ Qhi, ushort_t* __restrict__ Qlo,
    ushort_t* __restrict__ Khi, ushort_t* __restrict__ Klo,
    ushort_t* __restrict__ Vc) {
    __shared__ float t32[32][33];
    const int g = blockIdx.x;

    if (g < 1024) {
        // ---- prep Q: transpose fp32 -> [B][q][DK] bf16 hi/lo ----
        const int bx = g & 127, by = (g >> 7) & 3, b = g >> 9;
        const int d0 = by * 32, n0 = bx * 32;
        for (int l = threadIdx.x; l < 1024; l += 256) {
            int r = l >> 5, c = l & 31;
            t32[r][c] = qkey[((size_t)b * DK + d0 + r) * NQ + n0 + c];
        }
        __syncthreads();
        for (int l = threadIdx.x; l < 1024; l += 256) {
            int r = l >> 5, c = l & 31;
            float f = t32[c][r];
            unsigned short h = f2bf(f);
            unsigned short lw = f2bf(f - bf2f(h));
            size_t off = ((size_t)b * NQ + n0 + r) * DK + d0 + c;
            Qhi[off] = h;
            Qlo[off] = lw;
        }
        return;
    }
    if (g < 3072) {
        // ---- prep K: transpose + compacting gather -> swizzled image ----
        const int h0 = g - 1024;
        const int bx = h0 & 255, by = (h0 >> 8) & 3, b = h0 >> 10;
        const int d0 = by * 32, n0 = bx * 32;
        for (int l = threadIdx.x; l < 1024; l += 256) {
            int r = l >> 5, c = l & 31;
            t32[r][c] = mkey[((size_t)b * DK + d0 + r) * NM + n0 + c];
        }
        __syncthreads();
        for (int l = threadIdx.x; l < 1024; l += 256) {
            int r = l >> 5, c = l & 31;
            int m = n0 + r;
            if (mmask[b * NM + m] != 0) {
                int pos = cpos[b * NM + m];
                float f = t32[c][r];
                unsigned short hh = f2bf(f);
                unsigned short lw = f2bf(f - bf2f(hh));
                int d = d0 + c;
                size_t off = ((size_t)(b * NT + (pos >> 6))) * KTS
                           + ((pos >> 4) & 3) * 2048 + (d >> 5) * 512
                           + ((d >> 3) & 3) * 128 + (pos & 15) * 8 + (d & 7);
                Khi[off] = hh;
                Klo[off] = lw;
            }
        }
        return;
    }
    // ---- prep V: dense-read compaction -> swizzled image ----
    const int h0 = g - 3072;
    const int bx = h0 & 63;
    const int by = (h0 >> 6) % 9;
    const int b = h0 / 576;
    const int dv0 = bx * 8;
    if (by == 8) {   // tail-tile zero fill: pos in [cnt, nit*64)
        const int cnt = cnts[b];
        const int pend = ((cnt + 63) >> 6) * 64;
        const int dv = dv0 + (threadIdx.x >> 5);
        for (int p = cnt + (threadIdx.x & 31); p < pend; p += 32)
            Vc[vaddr(b, p, dv)] = 0;
        return;
    }
    const int m = by * 1024 + threadIdx.x * 4;
    const int4 mm = *(const int4*)(mmask + b * NM + m);
    const int4 cp = *(const int4*)(cpos + b * NM + m);
#pragma unroll
    for (int i = 0; i < 8; ++i) {
        const int dv = dv0 + i;
        const float4 v = *(const float4*)(mval + ((size_t)b * DV + dv) * NM + m);
        if (mm.x) Vc[vaddr(b, cp.x, dv)] = f2bf(v.x);
        if (mm.y) Vc[vaddr(b, cp.y, dv)] = f2bf(v.y);
        if (mm.z) Vc[vaddr(b, cp.z, dv)] = f2bf(v.z);
        if (mm.w) Vc[vaddr(b, cp.w, dv)] = f2bf(v.w);
    }
}

// ---------------------------------------------------------------------------
// stats-lite q64: hi*hi-only max per (q-tile64, m-quarter). Halves K-hi
// traffic vs q32. pv merges 4 parts + 8 margin. grid 512 = 64qt x 4 x 2b.
// ---------------------------------------------------------------------------
__global__ __launch_bounds__(256, 3) void stats_kernel(
    const ushort_t* __restrict__ Qhi, const ushort_t* __restrict__ Khi,
    const int* __restrict__ cnts, float* __restrict__ mpart) {
    const int t = threadIdx.x;
    const int lane = t & 63;
    const int w = t >> 6;
    const int quad = lane >> 4;
    const int col = lane & 15;
    const int bid = blockIdx.x;
    const int part = bid & 3;
    const int b = (bid >> 2) & 1;
    const int qb = (bid >> 3) * 64;

    const int cnt = cnts[b];
    const int nit = (cnt + 63) >> 6;
    const int it0 = (nit * part) >> 2;
    const int it1 = (nit * (part + 1)) >> 2;

    __shared__ float red_m[4][64];

    short8 qfh[4][4];
    {
        const ushort_t* qhp = Qhi + ((size_t)b * NQ + qb) * DK;
#pragma unroll
        for (int qt = 0; qt < 4; ++qt)
#pragma unroll
            for (int ks = 0; ks < 4; ++ks)
                qfh[qt][ks] = *(const short8*)(qhp + (size_t)(qt * 16 + col) * DK + ks * 32 + quad * 8);
    }

    const f32x4 zero4 = {0.f, 0.f, 0.f, 0.f};
    float mloc[4] = {-3.0e38f, -3.0e38f, -3.0e38f, -3.0e38f};
    const ushort_t* kh0 = Khi + w * 2048 + lane * 8;
    const size_t kbase = (size_t)(b * NT) * KTS;

#define LOADKH(A_, itn_) do {                                                 \
    const size_t ktb_ = kbase + (size_t)(itn_) * KTS;                         \
    _Pragma("unroll")                                                         \
    for (int ks_ = 0; ks_ < 4; ++ks_)                                         \
        A_[ks_] = *(const short8*)(kh0 + ktb_ + ks_ * 512);                   \
} while (0)

#define STPH(CK, NK, it_, itn_) do {                                          \
    LOADKH(NK, itn_);                                                         \
    f32x4 aS[4];                                                              \
    _Pragma("unroll")                                                         \
    for (int qt = 0; qt < 4; ++qt) aS[qt] = zero4;                            \
    _Pragma("unroll")                                                         \
    for (int ks = 0; ks < 4; ++ks)                                            \
        _Pragma("unroll")                                                     \
        for (int qt = 0; qt < 4; ++qt)                                        \
            aS[qt] = MF(CK[ks], qfh[qt][ks], aS[qt]);                         \
    const int mrow_ = (it_) * 64 + w * 16 + quad * 4;                         \
    _Pragma("unroll")                                                         \
    for (int r = 0; r < 4; ++r) {                                             \
        if (mrow_ + r < cnt) {                                                \
            _Pragma("unroll")                                                 \
            for (int qt = 0; qt < 4; ++qt)                                    \
                mloc[qt] = fmaxf(mloc[qt], aS[qt][r] * 40.0f);                \
        }                                                                     \
    }                                                                         \
} while (0)

    short8 kA[4], kB[4];
    int it = it0;
    if (it < it1) {
        LOADKH(kA, it);
        int itn;
        while (true) {
            itn = (it + 1 < it1) ? it + 1 : it;
            STPH(kA, kB, it, itn);
            if (++it >= it1) break;
            itn = (it + 1 < it1) ? it + 1 : it;
            STPH(kB, kA, it, itn);
            if (++it >= it1) break;
        }
    }
#undef STPH
#undef LOADKH

#pragma unroll
    for (int qt = 0; qt < 4; ++qt) {
        float m = mloc[qt];
        m = fmaxf(m, __shfl_xor(m, 16, 64));
        m = fmaxf(m, __shfl_xor(m, 32, 64));
        if (lane < 16) red_m[w][qt * 16 + col] = m;
    }
    __syncthreads();
    if (t < 64) {
        float M = -3.0e38f;
#pragma unroll
        for (int ww = 0; ww < 4; ++ww) M = fmaxf(M, red_m[ww][t]);
        mpart[((size_t)(b * 4 + part)) * NQ + qb + t] = M;
    }
}

// ---------------------------------------------------------------------------
// pv: r7 structure with 3 m-chunks -> grid 768 = exactly 3 blocks/CU (LDS
// 49KB x 3 = 147 < 160). bid low bits (b,dvh) for XCD K-locality. Exact
// per-chunk l via all-ones MFMA (dvh==0, w==0). 256 thr.
// ---------------------------------------------------------------------------
__global__ __launch_bounds__(256, 3) void pv_kernel(
    const ushort_t* __restrict__ Qhi, const ushort_t* __restrict__ Qlo,
    const ushort_t* __restrict__ Khi, const ushort_t* __restrict__ Klo,
    const ushort_t* __restrict__ Vimg, const int* __restrict__ cnts,
    const float* __restrict__ mpart, float* __restrict__ out0,
    float* __restrict__ out1, float* __restrict__ out2,
    float* __restrict__ lsum) {
    const int t = threadIdx.x;
    const int lane = t & 63;
    const int w = t >> 6;
    const int quad = lane >> 4;
    const int col = lane & 15;
    const int bid = blockIdx.x;
    const int b = bid & 1;
    const int dvh = (bid >> 1) & 1;
    const int r3 = bid >> 2;
    const int chunk = r3 % 3;
    const int qb = (r3 / 3) * 64;

    const int cnt = cnts[b];
    const int nit = (cnt + 63) >> 6;
    const int it0 = (nit * chunk) / 3;
    const int it1 = (nit * (chunk + 1)) / 3;

    __shared__ __align__(16) ushort_t Q_s[2][4][4][512];     // 32 KB
    __shared__ __align__(16) ushort_t P_s[2][64][68];        // 17.4 KB

    // inline finalize: merge 4 stats parts + margin for dropped lo-products
    float gm[4];
#pragma unroll
    for (int qt = 0; qt < 4; ++qt) {
        float M = -3.0e38f;
#pragma unroll
        for (int c = 0; c < 4; ++c)
            M = fmaxf(M, mpart[((size_t)(b * 4 + c)) * NQ + qb + qt * 16 + col]);
        gm[qt] = M + 8.0f;
    }

    {   // stage Q hi/lo into LDS fragment layout (row r = t>>2, dk chunk t&3)
        const int r = t >> 2, ks4 = t & 3;
        const int qt_ = r >> 4, col_ = r & 15;
        const ushort_t* qhp = Qhi + ((size_t)b * NQ + qb + r) * DK + ks4 * 32;
        const ushort_t* qlp = Qlo + ((size_t)b * NQ + qb + r) * DK + ks4 * 32;
#pragma unroll
        for (int qd = 0; qd < 4; ++qd) {
            *(short8*)&Q_s[0][qt_][ks4][qd * 128 + col_ * 8] = *(const short8*)(qhp + qd * 8);
            *(short8*)&Q_s[1][qt_][ks4][qd * 128 + col_ * 8] = *(const short8*)(qlp + qd * 8);
        }
    }
    __syncthreads();

    const ushort_t* kh0 = Khi + w * 2048 + lane * 8;
    const ushort_t* kl0 = Klo + w * 2048 + lane * 8;
    const size_t kbase = (size_t)(b * NT) * KTS;
    const ushort_t* vl0 = Vimg + ((size_t)(b * NT) * 2 + dvh) * VTILE
                        + w * 4096 + lane * 8;

    const f32x4 zero4 = {0.f, 0.f, 0.f, 0.f};
    const short8 vones = {(short)0x3F80, (short)0x3F80, (short)0x3F80,
                          (short)0x3F80, (short)0x3F80, (short)0x3F80,
                          (short)0x3F80, (short)0x3F80};
    const bool doL = (dvh == 0) && (w == 0);
    f32x4 accO[4][4];   // [vt][qt]
#pragma unroll
    for (int vt = 0; vt < 4; ++vt)
#pragma unroll
        for (int qt = 0; qt < 4; ++qt) accO[vt][qt] = zero4;
    f32x4 accL[4];
#pragma unroll
    for (int qt = 0; qt < 4; ++qt) accL[qt] = zero4;

    for (int it = it0; it < it1; ++it) {
        const int pb = (it - it0) & 1;
        // ---- K frags (single-buffered; consumed by QK below) ----
        short8 kh[4], kl[4];
        LOADK(kh, kl, it);
        // ---- QK: Q limbs streamed from LDS (3 limb-products) ----
        f32x4 aS[4];
#pragma unroll
        for (int qt = 0; qt < 4; ++qt) aS[qt] = zero4;
#pragma unroll
        for (int qt = 0; qt < 4; ++qt) {
#pragma unroll
            for (int ks = 0; ks < 4; ++ks) {
                const short8 qh = *(const short8*)&Q_s[0][qt][ks][lane * 8];
                const short8 ql = *(const short8*)&Q_s[1][qt][ks][lane * 8];
                aS[qt] = MF(kh[ks], qh, aS[qt]);
                aS[qt] = MF(kh[ks], ql, aS[qt]);
                aS[qt] = MF(kl[ks], qh, aS[qt]);
            }
        }
        // ---- V frags (issued here; stay in flight across the barrier) ----
        const ushort_t* vp = vl0 + (size_t)it * (2 * VTILE);
        short8 vf[4][2];
#pragma unroll
        for (int vt = 0; vt < 4; ++vt) {
            vf[vt][0] = *(const short8*)(vp + vt * 1024);
            vf[vt][1] = *(const short8*)(vp + vt * 1024 + 512);
        }
        // ---- P = exp(s - gmax) -> LDS (double-buffered) ----
        const int mrow = it * 64 + w * 16 + quad * 4;
#pragma unroll
        for (int qt = 0; qt < 4; ++qt) {
            float p[4];
#pragma unroll
            for (int r = 0; r < 4; ++r)
                p[r] = (mrow + r < cnt) ? __expf(aS[qt][r] * 40.0f - gm[qt]) : 0.0f;
            ushort4 pk;
            pk.x = f2bf(p[0]); pk.y = f2bf(p[1]);
            pk.z = f2bf(p[2]); pk.w = f2bf(p[3]);
            *(ushort4*)&P_s[pb][qt * 16 + col][w * 16 + quad * 4] = pk;
        }
        asm volatile("s_waitcnt lgkmcnt(0)" ::: "memory");
        __builtin_amdgcn_s_barrier();
        __builtin_amdgcn_sched_barrier(0);
        // ---- PV ----
#pragma unroll
        for (int k2 = 0; k2 < 2; ++k2) {
            short8 pq[4];
#pragma unroll
            for (int qt = 0; qt < 4; ++qt)
                pq[qt] = *(const short8*)&P_s[pb][qt * 16 + col][k2 * 32 + quad * 8];
#pragma unroll
            for (int vt = 0; vt < 4; ++vt)
#pragma unroll
                for (int qt = 0; qt < 4; ++qt)
                    accO[vt][qt] = MF(vf[vt][k2], pq[qt], accO[vt][qt]);
            if (doL) {
#pragma unroll
                for (int qt = 0; qt < 4; ++qt)
                    accL[qt] = MF(vones, pq[qt], accL[qt]);
            }
        }
    }

    // ---- epilogue: raw partial sums (normalization+gating in combine) ----
    float* pbase = (chunk == 0) ? out0 : ((chunk == 1) ? out1 : out2);
#pragma unroll
    for (int qt = 0; qt < 4; ++qt) {
        const int q = qb + qt * 16 + col;
#pragma unroll
        for (int vt = 0; vt < 4; ++vt)
#pragma unroll
            for (int r = 0; r < 4; ++r) {
                int dv = dvh * 256 + w * 64 + vt * 16 + quad * 4 + r;
                pbase[((size_t)b * DV + dv) * NQ + q] = accO[vt][qt][r];
            }
    }
    // exact per-chunk softmax denominator (all rows of accL identical)
    if (doL && lane < 16) {
#pragma unroll
        for (int qt = 0; qt < 4; ++qt)
            lsum[((size_t)(b * 3 + chunk)) * NQ + qb + qt * 16 + col] = accL[qt][0];
    }
}

// ---------------------------------------------------------------------------
// combine: out = gated (p0+p1+p2) / (l0+l1+l2)   (p0 aliases out)
// ---------------------------------------------------------------------------
__global__ __launch_bounds__(256) void combine_kernel(
    const float* p0, const float* __restrict__ p1,
    const float* __restrict__ p2, const float* __restrict__ lsum,
    const int* __restrict__ cnts, const int* __restrict__ qflags,
    const int* __restrict__ qmask, float* out) {
    const size_t i = ((size_t)blockIdx.x * 256 + threadIdx.x) * 4;
    const int b = (int)(i >> 21);          // DV*NQ = 2^21
    const int q = (int)(i & (NQ - 1));
    f32x4 a = *(const f32x4*)(p0 + i);
    f32x4 c = *(const f32x4*)(p1 + i);
    f32x4 d = *(const f32x4*)(p2 + i);
    f32x4 l0 = *(const f32x4*)(lsum + (size_t)(b * 3) * NQ + q);
    f32x4 l1 = *(const f32x4*)(lsum + (size_t)(b * 3 + 1) * NQ + q);
    f32x4 l2 = *(const f32x4*)(lsum + (size_t)(b * 3 + 2) * NQ + q);
    const int4 qm = *(const int4*)(qmask + b * NQ + q);
    const bool bv = (qflags[b] != 0) && (cnts[b] > 0);
    f32x4 r;
    float lv;
    lv = l0[0] + l1[0] + l2[0]; r[0] = (bv && qm.x && lv > 0.f) ? (a[0] + c[0] + d[0]) / lv : 0.f;
    lv = l0[1] + l1[1] + l2[1]; r[1] = (bv && qm.y && lv > 0.f) ? (a[1] + c[1] + d[1]) / lv : 0.f;
    lv = l0[2] + l1[2] + l2[2]; r[2] = (bv && qm.z && lv > 0.f) ? (a[2] + c[2] + d[2]) / lv : 0.f;
    lv = l0[3] + l1[3] + l2[3]; r[3] = (bv && qm.w && lv > 0.f) ? (a[3] + c[3] + d[3]) / lv : 0.f;
    *(f32x4*)(out + i) = r;
}

// ---------------------------------------------------------------------------
extern "C" void kernel_launch(void* const* d_in, const int* in_sizes, int n_in,
                              void* d_out, int out_size, void* d_ws, size_t ws_size,
                              hipStream_t stream) {
    const float* qkey  = (const float*)d_in[0];
    // d_in[1] (qval) unused by the reference
    const int*   qmask = (const int*)d_in[2];
    const float* mkey  = (const float*)d_in[3];
    const float* mval  = (const float*)d_in[4];
    const int*   mmask = (const int*)d_in[5];
    float* out = (float*)d_out;

    char* ws = (char*)d_ws;
    size_t off = 0;
    const size_t QS  = (size_t)BATCH * NQ * DK * 2;          // 2 MB each
    const size_t KS2 = (size_t)BATCH * NM * DK * 2;          // 4 MB each (swizzled)
    const size_t VS  = (size_t)BATCH * NT * 2 * VTILE * 2;   // 16 MB
    const size_t OS  = (size_t)BATCH * DV * NQ * 4;          // 16.8 MB
    ushort_t* Qhi = (ushort_t*)(ws + off); off += QS;
    ushort_t* Qlo = (ushort_t*)(ws + off); off += QS;
    ushort_t* Khi = (ushort_t*)(ws + off); off += KS2;
    ushort_t* Klo = (ushort_t*)(ws + off); off += KS2;
    ushort_t* Vc  = (ushort_t*)(ws + off); off += VS;
    float* part1  = (float*)(ws + off); off += OS;           // chunk-1 partial
    float* part2  = (float*)(ws + off); off += OS;           // chunk-2 partial
    float* mpart  = (float*)(ws + off); off += (size_t)BATCH * 4 * NQ * 4;
    float* lsum   = (float*)(ws + off); off += (size_t)BATCH * 3 * NQ * 4;
    int* cidx     = (int*)(ws + off); off += (size_t)BATCH * NM * 4;
    int* cpos     = (int*)(ws + off); off += (size_t)BATCH * NM * 4;
    int* cnts     = (int*)(ws + off); off += 64;
    int* qflags   = (int*)(ws + off); off += 64;

    scan_kernel<<<BATCH, 1024, 0, stream>>>(qmask, mmask, cidx, cpos, cnts, qflags);

    prep_all_kernel<<<4224, 256, 0, stream>>>(
        qkey, mkey, mval, mmask, cpos, cnts, Qhi, Qlo, Khi, Klo, Vc);

    stats_kernel<<<(NQ / 64) * 8, 256, 0, stream>>>(Qhi, Khi, cnts, mpart);

    pv_kernel<<<(NQ / 64) * 12, 256, 0, stream>>>(
        Qhi, Qlo, Khi, Klo, Vc, cnts, mpart, out, part1, part2, lsum);

    combine_kernel<<<(int)((size_t)BATCH * DV * NQ / 1024), 256, 0, stream>>>(
        out, part1, part2, lsum, cnts, qflags, qmask, out);
}

// Round 9
// 221.603 us; speedup vs baseline: 1.0714x; 1.0556x over previous
//
#include <hip/hip_runtime.h>
#include <hip/hip_fp16.h>

#define NQ 4096
#define NM 8192
#define DK 128
#define DV 512
#define BATCH 2
#define NT (NM / 64)        // 128 m-tiles per batch
#define KTS 8192            // shorts per K tile: 64 rows x 128 dk (tile-linear swizzled)
#define VTILE 16384         // shorts per (b, mtile, dvh) V tile: 256 dv x 64 m

typedef __attribute__((ext_vector_type(8))) short short8;
typedef __attribute__((ext_vector_type(4))) float f32x4;
typedef unsigned short ushort_t;

#define MF(A_, B_, C_) __builtin_amdgcn_mfma_f32_16x16x32_bf16(A_, B_, C_, 0, 0, 0)

static __device__ __forceinline__ unsigned short f2bf(float x) {
    union { float f; unsigned int u; } c; c.f = x;
    unsigned int u = c.u;
    return (unsigned short)((u + 0x7FFFu + ((u >> 16) & 1u)) >> 16);
}
static __device__ __forceinline__ float bf2f(unsigned short h) {
    union { unsigned int u; float f; } c; c.u = ((unsigned int)h) << 16;
    return c.f;
}
static __device__ __forceinline__ ushort_t f2h(float x) {
    __half h = __float2half(x);
    return *(ushort_t*)&h;
}
static __device__ __forceinline__ float h2f(ushort_t u) {
    __half h = *(__half*)&u;
    return __half2float(h);
}

// swizzled V-image address for (compacted pos, dv) within batch image
static __device__ __forceinline__ size_t vaddr(int b, int pos, int dv) {
    const int mt = pos >> 6, m64 = pos & 63;
    const int dvh = dv >> 8, rr = dv & 255;
    return (((size_t)(b * NT + mt) * 2 + dvh) * VTILE)
         + (rr >> 6) * 4096 + ((rr >> 4) & 3) * 1024
         + (m64 >> 5) * 512
         + ((((m64 >> 4) & 1) * 2 + ((m64 >> 3) & 1)) * 128)
         + (rr & 15) * 8 + (m64 & 7);
}

// K-tile register fragment load (1KB contiguous per wave per b128)
#define LOADK(AH, AL, itn_) do {                                              \
    const size_t ktb_ = kbase + (size_t)(itn_) * KTS;                         \
    _Pragma("unroll")                                                         \
    for (int ks_ = 0; ks_ < 4; ++ks_) {                                       \
        AH[ks_] = *(const short8*)(kh0 + ktb_ + ks_ * 512);                   \
        AL[ks_] = *(const short8*)(kl0 + ktb_ + ks_ * 512);                   \
    }                                                                         \
} while (0)

// ---------------------------------------------------------------------------
// scan: per-batch compaction of mmask (shfl wave scans). Unchanged.
// ---------------------------------------------------------------------------
__global__ __launch_bounds__(1024) void scan_kernel(
    const int* __restrict__ qmask, const int* __restrict__ mmask,
    int* __restrict__ cidx, int* __restrict__ cpos,
    int* __restrict__ cnts, int* __restrict__ qflags) {
    const int b = blockIdx.x;
    const int t = threadIdx.x;
    const int lane = t & 63;
    const int w = t >> 6;
    __shared__ int wsum[16];
    __shared__ int qsh;

    const int* mp = mmask + b * NM;
    const int base = t * 8;
    int val[8];
#pragma unroll
    for (int i = 0; i < 8; ++i) val[i] = (mp[base + i] != 0);
    int c0 = 0;
#pragma unroll
    for (int i = 0; i < 8; ++i) c0 += val[i];

    int c = c0;
#pragma unroll
    for (int off = 1; off < 64; off <<= 1) {
        int n = __shfl_up(c, off, 64);
        if (lane >= off) c += n;
    }
    if (lane == 63) wsum[w] = c;
    if (t == 0) qsh = 0;
    __syncthreads();
    if (t == 0) {
        int s = 0;
#pragma unroll
        for (int i = 0; i < 16; ++i) { s += wsum[i]; wsum[i] = s; }
    }
    __syncthreads();
    const int wbase = (w == 0) ? 0 : wsum[w - 1];
    int run = wbase + (c - c0);
#pragma unroll
    for (int i = 0; i < 8; ++i) {
        int m = base + i;
        cpos[b * NM + m] = run;
        if (val[i]) { cidx[b * NM + run] = m; ++run; }
    }

    int qa = 0;
    for (int i = t; i < NQ; i += 1024) qa |= (qmask[b * NQ + i] != 0);
    if (qa) atomicOr(&qsh, 1);
    __syncthreads();
    if (t == 0) { cnts[b] = wsum[15]; qflags[b] = qsh; }
}

// ---------------------------------------------------------------------------
// prep QK: blocks [0,1024) transpose Q -> bf16 hi/lo; [1024,3072) transpose +
// compact K -> swizzled image. (Split from prep_all for profiling visibility.)
// ---------------------------------------------------------------------------
__global__ __launch_bounds__(256) void prep_qk_kernel(
    const float* __restrict__ qkey, const float* __restrict__ mkey,
    const int* __restrict__ mmask, const int* __restrict__ cpos,
    ushort_t* __restrict__ Qhi, ushort_t* __restrict__ Qlo,
    ushort_t* __restrict__ Khi, ushort_t* __restrict__ Klo) {
    __shared__ float t32[32][33];
    const int g = blockIdx.x;

    if (g < 1024) {
        const int bx = g & 127, by = (g >> 7) & 3, b = g >> 9;
        const int d0 = by * 32, n0 = bx * 32;
        for (int l = threadIdx.x; l < 1024; l += 256) {
            int r = l >> 5, c = l & 31;
            t32[r][c] = qkey[((size_t)b * DK + d0 + r) * NQ + n0 + c];
        }
        __syncthreads();
        for (int l = threadIdx.x; l < 1024; l += 256) {
            int r = l >> 5, c = l & 31;
            float f = t32[c][r];
            unsigned short h = f2bf(f);
            unsigned short lw = f2bf(f - bf2f(h));
            size_t off = ((size_t)b * NQ + n0 + r) * DK + d0 + c;
            Qhi[off] = h;
            Qlo[off] = lw;
        }
        return;
    }
    const int h0 = g - 1024;
    const int bx = h0 & 255, by = (h0 >> 8) & 3, b = h0 >> 10;
    const int d0 = by * 32, n0 = bx * 32;
    for (int l = threadIdx.x; l < 1024; l += 256) {
        int r = l >> 5, c = l & 31;
        t32[r][c] = mkey[((size_t)b * DK + d0 + r) * NM + n0 + c];
    }
    __syncthreads();
    for (int l = threadIdx.x; l < 1024; l += 256) {
        int r = l >> 5, c = l & 31;
        int m = n0 + r;
        if (mmask[b * NM + m] != 0) {
            int pos = cpos[b * NM + m];
            float f = t32[c][r];
            unsigned short hh = f2bf(f);
            unsigned short lw = f2bf(f - bf2f(hh));
            int d = d0 + c;
            size_t off = ((size_t)(b * NT + (pos >> 6))) * KTS
                       + ((pos >> 4) & 3) * 2048 + (d >> 5) * 512
                       + ((d >> 3) & 3) * 128 + (pos & 15) * 8 + (d & 7);
            Khi[off] = hh;
            Klo[off] = lw;
        }
    }
}

// ---------------------------------------------------------------------------
// prep V: dense-read compaction -> swizzled image. grid (DV/8, 9, B), 256 thr.
// ---------------------------------------------------------------------------
__global__ __launch_bounds__(256) void prep_v_kernel(
    const float* __restrict__ src, const int* __restrict__ mmask,
    const int* __restrict__ cpos, const int* __restrict__ cnts,
    ushort_t* __restrict__ dst) {
    const int b = blockIdx.z;
    const int dv0 = blockIdx.x * 8;
    if (blockIdx.y == 8) {   // tail-tile zero fill: pos in [cnt, nit*64)
        const int cnt = cnts[b];
        const int pend = ((cnt + 63) >> 6) * 64;
        const int dv = dv0 + (threadIdx.x >> 5);
        for (int p = cnt + (threadIdx.x & 31); p < pend; p += 32)
            dst[vaddr(b, p, dv)] = 0;
        return;
    }
    const int m = blockIdx.y * 1024 + threadIdx.x * 4;
    const int4 mm = *(const int4*)(mmask + b * NM + m);
    const int4 cp = *(const int4*)(cpos + b * NM + m);
#pragma unroll
    for (int i = 0; i < 8; ++i) {
        const int dv = dv0 + i;
        const float4 v = *(const float4*)(src + ((size_t)b * DV + dv) * NM + m);
        if (mm.x) dst[vaddr(b, cp.x, dv)] = f2bf(v.x);
        if (mm.y) dst[vaddr(b, cp.y, dv)] = f2bf(v.y);
        if (mm.z) dst[vaddr(b, cp.z, dv)] = f2bf(v.z);
        if (mm.w) dst[vaddr(b, cp.w, dv)] = f2bf(v.w);
    }
}

// ---------------------------------------------------------------------------
// stats-lite q64: hi*hi-only max per (q-tile64, m-quarter). pv merges + 8.
// grid 512 = 64qt x 4 x 2b, 256 thr.
// ---------------------------------------------------------------------------
__global__ __launch_bounds__(256, 3) void stats_kernel(
    const ushort_t* __restrict__ Qhi, const ushort_t* __restrict__ Khi,
    const int* __restrict__ cnts, float* __restrict__ mpart) {
    const int t = threadIdx.x;
    const int lane = t & 63;
    const int w = t >> 6;
    const int quad = lane >> 4;
    const int col = lane & 15;
    const int bid = blockIdx.x;
    const int part = bid & 3;
    const int b = (bid >> 2) & 1;
    const int qb = (bid >> 3) * 64;

    const int cnt = cnts[b];
    const int nit = (cnt + 63) >> 6;
    const int it0 = (nit * part) >> 2;
    const int it1 = (nit * (part + 1)) >> 2;

    __shared__ float red_m[4][64];

    short8 qfh[4][4];
    {
        const ushort_t* qhp = Qhi + ((size_t)b * NQ + qb) * DK;
#pragma unroll
        for (int qt = 0; qt < 4; ++qt)
#pragma unroll
            for (int ks = 0; ks < 4; ++ks)
                qfh[qt][ks] = *(const short8*)(qhp + (size_t)(qt * 16 + col) * DK + ks * 32 + quad * 8);
    }

    const f32x4 zero4 = {0.f, 0.f, 0.f, 0.f};
    float mloc[4] = {-3.0e38f, -3.0e38f, -3.0e38f, -3.0e38f};
    const ushort_t* kh0 = Khi + w * 2048 + lane * 8;
    const size_t kbase = (size_t)(b * NT) * KTS;

#define LOADKH(A_, itn_) do {                                                 \
    const size_t ktb_ = kbase + (size_t)(itn_) * KTS;                         \
    _Pragma("unroll")                                                         \
    for (int ks_ = 0; ks_ < 4; ++ks_)                                         \
        A_[ks_] = *(const short8*)(kh0 + ktb_ + ks_ * 512);                   \
} while (0)

#define STPH(CK, NK, it_, itn_) do {                                          \
    LOADKH(NK, itn_);                                                         \
    f32x4 aS[4];                                                              \
    _Pragma("unroll")                                                         \
    for (int qt = 0; qt < 4; ++qt) aS[qt] = zero4;                            \
    _Pragma("unroll")                                                         \
    for (int ks = 0; ks < 4; ++ks)                                            \
        _Pragma("unroll")                                                     \
        for (int qt = 0; qt < 4; ++qt)                                        \
            aS[qt] = MF(CK[ks], qfh[qt][ks], aS[qt]);                         \
    const int mrow_ = (it_) * 64 + w * 16 + quad * 4;                         \
    _Pragma("unroll")                                                         \
    for (int r = 0; r < 4; ++r) {                                             \
        if (mrow_ + r < cnt) {                                                \
            _Pragma("unroll")                                                 \
            for (int qt = 0; qt < 4; ++qt)                                    \
                mloc[qt] = fmaxf(mloc[qt], aS[qt][r] * 40.0f);                \
        }                                                                     \
    }                                                                         \
} while (0)

    short8 kA[4], kB[4];
    int it = it0;
    if (it < it1) {
        LOADKH(kA, it);
        int itn;
        while (true) {
            itn = (it + 1 < it1) ? it + 1 : it;
            STPH(kA, kB, it, itn);
            if (++it >= it1) break;
            itn = (it + 1 < it1) ? it + 1 : it;
            STPH(kB, kA, it, itn);
            if (++it >= it1) break;
        }
    }
#undef STPH
#undef LOADKH

#pragma unroll
    for (int qt = 0; qt < 4; ++qt) {
        float m = mloc[qt];
        m = fmaxf(m, __shfl_xor(m, 16, 64));
        m = fmaxf(m, __shfl_xor(m, 32, 64));
        if (lane < 16) red_m[w][qt * 16 + col] = m;
    }
    __syncthreads();
    if (t < 64) {
        float M = -3.0e38f;
#pragma unroll
        for (int ww = 0; ww < 4; ++ww) M = fmaxf(M, red_m[ww][t]);
        mpart[((size_t)(b * 4 + part)) * NQ + qb + t] = M;
    }
}

// ---------------------------------------------------------------------------
// pv: r8 structure (q64, 3 m-chunks, grid 768 = 3 blocks/CU) + fp16 partial
// writes (halved WRITE traffic) + s_setprio around MFMA clusters (T5: 3
// independent blocks/CU at different phases -> scheduler role-diversity).
// ---------------------------------------------------------------------------
__global__ __launch_bounds__(256, 3) void pv_kernel(
    const ushort_t* __restrict__ Qhi, const ushort_t* __restrict__ Qlo,
    const ushort_t* __restrict__ Khi, const ushort_t* __restrict__ Klo,
    const ushort_t* __restrict__ Vimg, const int* __restrict__ cnts,
    const float* __restrict__ mpart, ushort_t* __restrict__ out0,
    ushort_t* __restrict__ out1, ushort_t* __restrict__ out2,
    float* __restrict__ lsum) {
    const int t = threadIdx.x;
    const int lane = t & 63;
    const int w = t >> 6;
    const int quad = lane >> 4;
    const int col = lane & 15;
    const int bid = blockIdx.x;
    const int b = bid & 1;
    const int dvh = (bid >> 1) & 1;
    const int r3 = bid >> 2;
    const int chunk = r3 % 3;
    const int qb = (r3 / 3) * 64;

    const int cnt = cnts[b];
    const int nit = (cnt + 63) >> 6;
    const int it0 = (nit * chunk) / 3;
    const int it1 = (nit * (chunk + 1)) / 3;

    __shared__ __align__(16) ushort_t Q_s[2][4][4][512];     // 32 KB
    __shared__ __align__(16) ushort_t P_s[2][64][68];        // 17.4 KB

    // inline finalize: merge 4 stats parts + margin for dropped lo-products
    float gm[4];
#pragma unroll
    for (int qt = 0; qt < 4; ++qt) {
        float M = -3.0e38f;
#pragma unroll
        for (int c = 0; c < 4; ++c)
            M = fmaxf(M, mpart[((size_t)(b * 4 + c)) * NQ + qb + qt * 16 + col]);
        gm[qt] = M + 8.0f;
    }

    {   // stage Q hi/lo into LDS fragment layout (row r = t>>2, dk chunk t&3)
        const int r = t >> 2, ks4 = t & 3;
        const int qt_ = r >> 4, col_ = r & 15;
        const ushort_t* qhp = Qhi + ((size_t)b * NQ + qb + r) * DK + ks4 * 32;
        const ushort_t* qlp = Qlo + ((size_t)b * NQ + qb + r) * DK + ks4 * 32;
#pragma unroll
        for (int qd = 0; qd < 4; ++qd) {
            *(short8*)&Q_s[0][qt_][ks4][qd * 128 + col_ * 8] = *(const short8*)(qhp + qd * 8);
            *(short8*)&Q_s[1][qt_][ks4][qd * 128 + col_ * 8] = *(const short8*)(qlp + qd * 8);
        }
    }
    __syncthreads();

    const ushort_t* kh0 = Khi + w * 2048 + lane * 8;
    const ushort_t* kl0 = Klo + w * 2048 + lane * 8;
    const size_t kbase = (size_t)(b * NT) * KTS;
    const ushort_t* vl0 = Vimg + ((size_t)(b * NT) * 2 + dvh) * VTILE
                        + w * 4096 + lane * 8;

    const f32x4 zero4 = {0.f, 0.f, 0.f, 0.f};
    const short8 vones = {(short)0x3F80, (short)0x3F80, (short)0x3F80,
                          (short)0x3F80, (short)0x3F80, (short)0x3F80,
                          (short)0x3F80, (short)0x3F80};
    const bool doL = (dvh == 0) && (w == 0);
    f32x4 accO[4][4];   // [vt][qt]
#pragma unroll
    for (int vt = 0; vt < 4; ++vt)
#pragma unroll
        for (int qt = 0; qt < 4; ++qt) accO[vt][qt] = zero4;
    f32x4 accL[4];
#pragma unroll
    for (int qt = 0; qt < 4; ++qt) accL[qt] = zero4;

    for (int it = it0; it < it1; ++it) {
        const int pb = (it - it0) & 1;
        // ---- K frags (single-buffered; consumed by QK below) ----
        short8 kh[4], kl[4];
        LOADK(kh, kl, it);
        // ---- QK: Q limbs streamed from LDS (3 limb-products) ----
        f32x4 aS[4];
#pragma unroll
        for (int qt = 0; qt < 4; ++qt) aS[qt] = zero4;
        __builtin_amdgcn_s_setprio(1);
#pragma unroll
        for (int qt = 0; qt < 4; ++qt) {
#pragma unroll
            for (int ks = 0; ks < 4; ++ks) {
                const short8 qh = *(const short8*)&Q_s[0][qt][ks][lane * 8];
                const short8 ql = *(const short8*)&Q_s[1][qt][ks][lane * 8];
                aS[qt] = MF(kh[ks], qh, aS[qt]);
                aS[qt] = MF(kh[ks], ql, aS[qt]);
                aS[qt] = MF(kl[ks], qh, aS[qt]);
            }
        }
        __builtin_amdgcn_s_setprio(0);
        // ---- V frags (issued here; stay in flight across the barrier) ----
        const ushort_t* vp = vl0 + (size_t)it * (2 * VTILE);
        short8 vf[4][2];
#pragma unroll
        for (int vt = 0; vt < 4; ++vt) {
            vf[vt][0] = *(const short8*)(vp + vt * 1024);
            vf[vt][1] = *(const short8*)(vp + vt * 1024 + 512);
        }
        // ---- P = exp(s - gmax) -> LDS (double-buffered) ----
        const int mrow = it * 64 + w * 16 + quad * 4;
#pragma unroll
        for (int qt = 0; qt < 4; ++qt) {
            float p[4];
#pragma unroll
            for (int r = 0; r < 4; ++r)
                p[r] = (mrow + r < cnt) ? __expf(aS[qt][r] * 40.0f - gm[qt]) : 0.0f;
            ushort4 pk;
            pk.x = f2bf(p[0]); pk.y = f2bf(p[1]);
            pk.z = f2bf(p[2]); pk.w = f2bf(p[3]);
            *(ushort4*)&P_s[pb][qt * 16 + col][w * 16 + quad * 4] = pk;
        }
        asm volatile("s_waitcnt lgkmcnt(0)" ::: "memory");
        __builtin_amdgcn_s_barrier();
        __builtin_amdgcn_sched_barrier(0);
        // ---- PV ----
        __builtin_amdgcn_s_setprio(1);
#pragma unroll
        for (int k2 = 0; k2 < 2; ++k2) {
            short8 pq[4];
#pragma unroll
            for (int qt = 0; qt < 4; ++qt)
                pq[qt] = *(const short8*)&P_s[pb][qt * 16 + col][k2 * 32 + quad * 8];
#pragma unroll
            for (int vt = 0; vt < 4; ++vt)
#pragma unroll
                for (int qt = 0; qt < 4; ++qt)
                    accO[vt][qt] = MF(vf[vt][k2], pq[qt], accO[vt][qt]);
            if (doL) {
#pragma unroll
                for (int qt = 0; qt < 4; ++qt)
                    accL[qt] = MF(vones, pq[qt], accL[qt]);
            }
        }
        __builtin_amdgcn_s_setprio(0);
    }

    // ---- epilogue: fp16 raw partial sums (normalize+gate in combine) ----
    ushort_t* pbase = (chunk == 0) ? out0 : ((chunk == 1) ? out1 : out2);
#pragma unroll
    for (int qt = 0; qt < 4; ++qt) {
        const int q = qb + qt * 16 + col;
#pragma unroll
        for (int vt = 0; vt < 4; ++vt)
#pragma unroll
            for (int r = 0; r < 4; ++r) {
                int dv = dvh * 256 + w * 64 + vt * 16 + quad * 4 + r;
                pbase[((size_t)b * DV + dv) * NQ + q] = f2h(accO[vt][qt][r]);
            }
    }
    // exact per-chunk softmax denominator (all rows of accL identical)
    if (doL && lane < 16) {
#pragma unroll
        for (int qt = 0; qt < 4; ++qt)
            lsum[((size_t)(b * 3 + chunk)) * NQ + qb + qt * 16 + col] = accL[qt][0];
    }
}

// ---------------------------------------------------------------------------
// combine: out = gated (p0+p1+p2) / (l0+l1+l2), fp16 partials -> fp32 out
// ---------------------------------------------------------------------------
__global__ __launch_bounds__(256) void combine_kernel(
    const ushort_t* __restrict__ p0, const ushort_t* __restrict__ p1,
    const ushort_t* __restrict__ p2, const float* __restrict__ lsum,
    const int* __restrict__ cnts, const int* __restrict__ qflags,
    const int* __restrict__ qmask, float* __restrict__ out) {
    const size_t i = ((size_t)blockIdx.x * 256 + threadIdx.x) * 4;
    const int b = (int)(i >> 21);          // DV*NQ = 2^21
    const int q = (int)(i & (NQ - 1));
    ushort4 a4 = *(const ushort4*)(p0 + i);
    ushort4 c4 = *(const ushort4*)(p1 + i);
    ushort4 d4 = *(const ushort4*)(p2 + i);
    f32x4 l0 = *(const f32x4*)(lsum + (size_t)(b * 3) * NQ + q);
    f32x4 l1 = *(const f32x4*)(lsum + (size_t)(b * 3 + 1) * NQ + q);
    f32x4 l2 = *(const f32x4*)(lsum + (size_t)(b * 3 + 2) * NQ + q);
    const int4 qm = *(const int4*)(qmask + b * NQ + q);
    const bool bv = (qflags[b] != 0) && (cnts[b] > 0);
    f32x4 r;
    float lv;
    lv = l0[0] + l1[0] + l2[0];
    r[0] = (bv && qm.x && lv > 0.f) ? (h2f(a4.x) + h2f(c4.x) + h2f(d4.x)) / lv : 0.f;
    lv = l0[1] + l1[1] + l2[1];
    r[1] = (bv && qm.y && lv > 0.f) ? (h2f(a4.y) + h2f(c4.y) + h2f(d4.y)) / lv : 0.f;
    lv = l0[2] + l1[2] + l2[2];
    r[2] = (bv && qm.z && lv > 0.f) ? (h2f(a4.z) + h2f(c4.z) + h2f(d4.z)) / lv : 0.f;
    lv = l0[3] + l1[3] + l2[3];
    r[3] = (bv && qm.w && lv > 0.f) ? (h2f(a4.w) + h2f(c4.w) + h2f(d4.w)) / lv : 0.f;
    *(f32x4*)(out + i) = r;
}

// ---------------------------------------------------------------------------
extern "C" void kernel_launch(void* const* d_in, const int* in_sizes, int n_in,
                              void* d_out, int out_size, void* d_ws, size_t ws_size,
                              hipStream_t stream) {
    const float* qkey  = (const float*)d_in[0];
    // d_in[1] (qval) unused by the reference
    const int*   qmask = (const int*)d_in[2];
    const float* mkey  = (const float*)d_in[3];
    const float* mval  = (const float*)d_in[4];
    const int*   mmask = (const int*)d_in[5];
    float* out = (float*)d_out;

    char* ws = (char*)d_ws;
    size_t off = 0;
    const size_t QS  = (size_t)BATCH * NQ * DK * 2;          // 2 MB each
    const size_t KS2 = (size_t)BATCH * NM * DK * 2;          // 4 MB each (swizzled)
    const size_t VS  = (size_t)BATCH * NT * 2 * VTILE * 2;   // 16 MB
    const size_t OS2 = (size_t)BATCH * DV * NQ * 2;          // 8.4 MB fp16 partial
    ushort_t* Qhi = (ushort_t*)(ws + off); off += QS;
    ushort_t* Qlo = (ushort_t*)(ws + off); off += QS;
    ushort_t* Khi = (ushort_t*)(ws + off); off += KS2;
    ushort_t* Klo = (ushort_t*)(ws + off); off += KS2;
    ushort_t* Vc  = (ushort_t*)(ws + off); off += VS;
    ushort_t* part0 = (ushort_t*)(ws + off); off += OS2;
    ushort_t* part1 = (ushort_t*)(ws + off); off += OS2;
    ushort_t* part2 = (ushort_t*)(ws + off); off += OS2;
    float* mpart  = (float*)(ws + off); off += (size_t)BATCH * 4 * NQ * 4;
    float* lsum   = (float*)(ws + off); off += (size_t)BATCH * 3 * NQ * 4;
    int* cidx     = (int*)(ws + off); off += (size_t)BATCH * NM * 4;
    int* cpos     = (int*)(ws + off); off += (size_t)BATCH * NM * 4;
    int* cnts     = (int*)(ws + off); off += 64;
    int* qflags   = (int*)(ws + off); off += 64;

    scan_kernel<<<BATCH, 1024, 0, stream>>>(qmask, mmask, cidx, cpos, cnts, qflags);

    prep_qk_kernel<<<3072, 256, 0, stream>>>(
        qkey, mkey, mmask, cpos, Qhi, Qlo, Khi, Klo);

    dim3 gv(DV / 8, 9, BATCH);
    prep_v_kernel<<<gv, 256, 0, stream>>>(mval, mmask, cpos, cnts, Vc);

    stats_kernel<<<(NQ / 64) * 8, 256, 0, stream>>>(Qhi, Khi, cnts, mpart);

    pv_kernel<<<(NQ / 64) * 12, 256, 0, stream>>>(
        Qhi, Qlo, Khi, Klo, Vc, cnts, mpart, part0, part1, part2, lsum);

    combine_kernel<<<(int)((size_t)BATCH * DV * NQ / 1024), 256, 0, stream>>>(
        part0, part1, part2, lsum, cnts, qflags, qmask, out);
}